// Round 5
// baseline (189.398 us; speedup 1.0000x reference)
//
#include <hip/hip_runtime.h>
#include <math.h>

#define BB 32
#define TT 8192
#define CCH 128
#define OO 64
#define DD 288
#define NFREQ 12
#define NIJ 144

typedef _Float16 v8h __attribute__((ext_vector_type(8)));
typedef float f32x4 __attribute__((ext_vector_type(4)));

// ---------------- K0: transpose heads [64][288] -> Ht [288][64] ----------------
__global__ __launch_bounds__(256) void k0_transpose_heads(const float* __restrict__ heads,
                                                          float* __restrict__ Ht) {
    int idx = blockIdx.x * 256 + threadIdx.x;
    if (idx < OO * DD) {
        int o = idx / DD;
        int d = idx - o * DD;
        Ht[d * OO + o] = heads[idx];
    }
}

// ---------------- K1: fourier emb + scores + softmax -> w [B][O][C] ----------------
#define IJ_CHUNK 36
#define EMB_LD 129

__global__ __launch_bounds__(256) void k1_weights(const float* __restrict__ pos,
                                                  const float* __restrict__ Ht,
                                                  float* __restrict__ w) {
    __shared__ float smem[2 * IJ_CHUNK * EMB_LD];   // 9288 floats = 37 KB
    float* cos_s = smem;
    float* sin_s = smem + IJ_CHUNK * EMB_LD;

    const int b = blockIdx.x;
    const int obase = blockIdx.y * 16;
    const int tid = threadIdx.x;
    const int c = tid & 127;
    const int hh = __builtin_amdgcn_readfirstlane(tid >> 7);  // wave-uniform

    const float* posb = pos + b * CCH * 2;
    const float S = 4.487989505128276f;  // 2*pi/1.4

    float accs[8];
#pragma unroll
    for (int k = 0; k < 8; ++k) accs[k] = 0.f;

#pragma unroll 1
    for (int cc = 0; cc < NIJ; cc += IJ_CHUNK) {
#pragma unroll 1
        for (int it = 0; it < (IJ_CHUNK * CCH) / 256; ++it) {
            int idx = it * 256 + tid;
            int ec = idx & 127;
            int ijl = idx >> 7;
            int ij = cc + ijl;
            int i = ij / NFREQ;
            int j = ij - i * NFREQ;
            float px = posb[2 * ec] + 0.2f;
            float py = posb[2 * ec + 1] + 0.2f;
            float ang = px * (S * (float)i) + py * (S * (float)j);
            float sv, cv;
            __sincosf(ang, &sv, &cv);
            cos_s[ijl * EMB_LD + ec] = cv;
            sin_s[ijl * EMB_LD + ec] = sv;
        }
        __syncthreads();
#pragma unroll 4
        for (int ijl = 0; ijl < IJ_CHUNK; ++ijl) {
            float cv = cos_s[ijl * EMB_LD + c];
            float sv = sin_s[ijl * EMB_LD + c];
            const float* hc = Ht + (cc + ijl) * OO + obase + hh * 8;
            const float* hs = Ht + (NIJ + cc + ijl) * OO + obase + hh * 8;
#pragma unroll
            for (int k = 0; k < 8; ++k) {
                accs[k] = fmaf(cv, hc[k], fmaf(sv, hs[k], accs[k]));
            }
        }
        __syncthreads();
    }

    // scores -> LDS [16][129]
    float* sc = smem;
#pragma unroll
    for (int k = 0; k < 8; ++k) {
        sc[(hh * 8 + k) * EMB_LD + c] = accs[k];
    }
    __syncthreads();

    // parallel softmax: o16 = tid>>4 owns one o-row; part = tid&15 owns 8 channels
    float* red  = smem + 16 * EMB_LD;        // 256 floats
    float* red2 = red + 256;                 // 256 floats
    const int o16 = tid >> 4;
    const int part = tid & 15;
    const float* srow = sc + o16 * EMB_LD + part * 8;

    float m = -1e30f;
#pragma unroll
    for (int j = 0; j < 8; ++j) m = fmaxf(m, srow[j]);
    red[o16 * 16 + part] = m;
    __syncthreads();
    float M = red[o16 * 16];
#pragma unroll
    for (int p = 1; p < 16; ++p) M = fmaxf(M, red[o16 * 16 + p]);

    float ev[8];
    float s = 0.f;
#pragma unroll
    for (int j = 0; j < 8; ++j) { ev[j] = __expf(srow[j] - M); s += ev[j]; }
    red2[o16 * 16 + part] = s;
    __syncthreads();
    float Sum = 0.f;
#pragma unroll
    for (int p = 0; p < 16; ++p) Sum += red2[o16 * 16 + p];
    float inv = 1.f / Sum;

    float* wrow = w + ((size_t)(b * OO + obase + o16)) * CCH + part * 8;
#pragma unroll
    for (int j = 0; j < 8; ++j) wrow[j] = ev[j] * inv;
}

// ---------------- K1b: pack weights into fp16 MFMA B-fragments ----------------
// B of mfma_f32_16x16x32_f16: col = lane&15, per-lane 8 k-elems (same indexing as
// the A side in k2 — any internal k-permutation cancels between A and B).
// frag index: (((b*4 + kc)*4 + ot)*64 + lane), 16B per lane.
__global__ __launch_bounds__(256) void k1b_frag(const float* __restrict__ w,
                                                uint4* __restrict__ fragH) {
    const int b = blockIdx.x;
    const int kc = blockIdx.y;
    const int ot = threadIdx.x >> 6;
    const int lane = threadIdx.x & 63;
    const int o = ot * 16 + (lane & 15);
    const int cbase = kc * 32 + (lane >> 4) * 8;
    const float* wrow = w + ((size_t)(b * OO + o)) * CCH + cbase;

    float4 a = *(const float4*)wrow;
    float4 c = *(const float4*)(wrow + 4);
    v8h h;
    h[0] = (_Float16)a.x; h[1] = (_Float16)a.y;
    h[2] = (_Float16)a.z; h[3] = (_Float16)a.w;
    h[4] = (_Float16)c.x; h[5] = (_Float16)c.y;
    h[6] = (_Float16)c.z; h[7] = (_Float16)c.w;

    union { uint4 u; v8h v; } u;
    u.v = h;
    fragH[((b * 4 + kc) * 4 + ot) * 64 + lane] = u.u;
}

// ---------------- K2: out[b,t,o] = sum_c eeg[b,t,c] * w[b,o,c] via fp16 MFMA ----
// 256 thr = 4 waves; wave owns 64 t-rows (4 tiles of 16). A: lane holds
// eeg[row=lane&15][8 k-elems], converted fp32->fp16 (RNE) on the fly. fp16 rel
// err 2^-12 on both operands, fp32 accumulate => abs err ~3e-3 << 1.4e-2 thresh.
// C/D: col=lane&15, row=(lane>>4)*4+reg (HW-verified m89). All acc[] indices
// compile-time constant (runtime-indexed ext-vector arrays go to scratch).
__global__ __launch_bounds__(256, 4) void k2_mfma(const float* __restrict__ eeg,
                                                  const uint4* __restrict__ fragH,
                                                  float* __restrict__ out) {
    const int b = blockIdx.y;
    const int t0 = blockIdx.x * 256;
    const int lane = threadIdx.x & 63;
    const int wv = __builtin_amdgcn_readfirstlane(threadIdx.x >> 6);
    const int r16 = lane & 15;
    const int kq = lane >> 4;

    const float* ebase = eeg + ((size_t)b * TT + t0 + wv * 64) * CCH;

    f32x4 acc[4][4];
#pragma unroll
    for (int tt = 0; tt < 4; ++tt)
#pragma unroll
        for (int ot = 0; ot < 4; ++ot)
            acc[tt][ot] = (f32x4){0.f, 0.f, 0.f, 0.f};

#pragma unroll 1
    for (int kc = 0; kc < 4; ++kc) {
        const uint4* fh = fragH + (size_t)((b * 4 + kc) * 4) * 64 + lane;
        v8h bh[4];
#pragma unroll
        for (int ot = 0; ot < 4; ++ot) {
            union { uint4 u; v8h v; } u;
            u.u = fh[ot * 64];
            bh[ot] = u.v;
        }
#pragma unroll 2
        for (int tt = 0; tt < 4; ++tt) {
            const float* ap = ebase + (size_t)(tt * 16 + r16) * CCH + kc * 32 + kq * 8;
            float4 v0 = *(const float4*)ap;
            float4 v1 = *(const float4*)(ap + 4);
            v8h ah;
            ah[0] = (_Float16)v0.x; ah[1] = (_Float16)v0.y;
            ah[2] = (_Float16)v0.z; ah[3] = (_Float16)v0.w;
            ah[4] = (_Float16)v1.x; ah[5] = (_Float16)v1.y;
            ah[6] = (_Float16)v1.z; ah[7] = (_Float16)v1.w;
#pragma unroll
            for (int ot = 0; ot < 4; ++ot) {
                acc[tt][ot] = __builtin_amdgcn_mfma_f32_16x16x32_f16(ah, bh[ot], acc[tt][ot], 0, 0, 0);
            }
        }
    }

    // epilogue: lane holds D[row = kq*4 + reg][col = r16] per tile
    const size_t orow0 = (size_t)b * TT + t0 + wv * 64;
#pragma unroll
    for (int tt = 0; tt < 4; ++tt) {
#pragma unroll
        for (int reg = 0; reg < 4; ++reg) {
            const size_t row = orow0 + tt * 16 + kq * 4 + reg;
#pragma unroll
            for (int ot = 0; ot < 4; ++ot) {
                out[row * OO + ot * 16 + r16] = acc[tt][ot][reg];
            }
        }
    }
}

extern "C" void kernel_launch(void* const* d_in, const int* in_sizes, int n_in,
                              void* d_out, int out_size, void* d_ws, size_t ws_size,
                              hipStream_t stream) {
    const float* eeg   = (const float*)d_in[0];   // [B,T,C]
    const float* pos   = (const float*)d_in[1];   // [B,C,2]
    const float* heads = (const float*)d_in[2];   // [O,D]
    float* out = (float*)d_out;                   // [B,T,O]

    char* ws = (char*)d_ws;
    float* Ht     = (float*)ws;                       // 288*64*4    = 73728 B
    float* w      = (float*)(ws + 73728);             // 32*64*128*4 = 1048576 B
    uint4* fragH  = (uint4*)(ws + 73728 + 1048576);   // 32*4*4*64*16 = 524288 B

    k0_transpose_heads<<<(OO * DD + 255) / 256, 256, 0, stream>>>(heads, Ht);
    k1_weights<<<dim3(BB, 4), 256, 0, stream>>>(pos, Ht, w);
    k1b_frag<<<dim3(BB, 4), 256, 0, stream>>>(w, fragH);
    k2_mfma<<<dim3(TT / 256, BB), 256, 0, stream>>>(eeg, fragH, out);
}

// Round 6
// 68.358 us; speedup vs baseline: 2.7707x; 2.7707x over previous
//
#include <hip/hip_runtime.h>
#include <math.h>

#define BB 32
#define TT 8192
#define CCH 128
#define OO 64
#define DD 288
#define NFREQ 12
#define NIJ 144

typedef _Float16 v8h __attribute__((ext_vector_type(8)));
typedef float f32x4 __attribute__((ext_vector_type(4)));

// ---------------- K0: transpose heads [64][288] -> Ht [288][64] ----------------
__global__ __launch_bounds__(256) void k0_transpose_heads(const float* __restrict__ heads,
                                                          float* __restrict__ Ht) {
    int idx = blockIdx.x * 256 + threadIdx.x;
    if (idx < OO * DD) {
        int o = idx / DD;
        int d = idx - o * DD;
        Ht[d * OO + o] = heads[idx];
    }
}

// ---------------- K1: fourier emb + scores + softmax -> w [B][O][C] ----------------
#define IJ_CHUNK 36
#define EMB_LD 129

__global__ __launch_bounds__(256) void k1_weights(const float* __restrict__ pos,
                                                  const float* __restrict__ Ht,
                                                  float* __restrict__ w) {
    __shared__ float smem[2 * IJ_CHUNK * EMB_LD];   // 9288 floats = 37 KB
    float* cos_s = smem;
    float* sin_s = smem + IJ_CHUNK * EMB_LD;

    const int b = blockIdx.x;
    const int obase = blockIdx.y * 16;
    const int tid = threadIdx.x;
    const int c = tid & 127;
    const int hh = __builtin_amdgcn_readfirstlane(tid >> 7);  // wave-uniform

    const float* posb = pos + b * CCH * 2;
    const float S = 4.487989505128276f;  // 2*pi/1.4

    float accs[8];
#pragma unroll
    for (int k = 0; k < 8; ++k) accs[k] = 0.f;

#pragma unroll 1
    for (int cc = 0; cc < NIJ; cc += IJ_CHUNK) {
#pragma unroll 1
        for (int it = 0; it < (IJ_CHUNK * CCH) / 256; ++it) {
            int idx = it * 256 + tid;
            int ec = idx & 127;
            int ijl = idx >> 7;
            int ij = cc + ijl;
            int i = ij / NFREQ;
            int j = ij - i * NFREQ;
            float px = posb[2 * ec] + 0.2f;
            float py = posb[2 * ec + 1] + 0.2f;
            float ang = px * (S * (float)i) + py * (S * (float)j);
            float sv, cv;
            __sincosf(ang, &sv, &cv);
            cos_s[ijl * EMB_LD + ec] = cv;
            sin_s[ijl * EMB_LD + ec] = sv;
        }
        __syncthreads();
#pragma unroll 4
        for (int ijl = 0; ijl < IJ_CHUNK; ++ijl) {
            float cv = cos_s[ijl * EMB_LD + c];
            float sv = sin_s[ijl * EMB_LD + c];
            const float* hc = Ht + (cc + ijl) * OO + obase + hh * 8;
            const float* hs = Ht + (NIJ + cc + ijl) * OO + obase + hh * 8;
#pragma unroll
            for (int k = 0; k < 8; ++k) {
                accs[k] = fmaf(cv, hc[k], fmaf(sv, hs[k], accs[k]));
            }
        }
        __syncthreads();
    }

    // scores -> LDS [16][129]
    float* sc = smem;
#pragma unroll
    for (int k = 0; k < 8; ++k) {
        sc[(hh * 8 + k) * EMB_LD + c] = accs[k];
    }
    __syncthreads();

    // parallel softmax: o16 = tid>>4 owns one o-row; part = tid&15 owns 8 channels
    float* red  = smem + 16 * EMB_LD;        // 256 floats
    float* red2 = red + 256;                 // 256 floats
    const int o16 = tid >> 4;
    const int part = tid & 15;
    const float* srow = sc + o16 * EMB_LD + part * 8;

    float m = -1e30f;
#pragma unroll
    for (int j = 0; j < 8; ++j) m = fmaxf(m, srow[j]);
    red[o16 * 16 + part] = m;
    __syncthreads();
    float M = red[o16 * 16];
#pragma unroll
    for (int p = 1; p < 16; ++p) M = fmaxf(M, red[o16 * 16 + p]);

    float ev[8];
    float s = 0.f;
#pragma unroll
    for (int j = 0; j < 8; ++j) { ev[j] = __expf(srow[j] - M); s += ev[j]; }
    red2[o16 * 16 + part] = s;
    __syncthreads();
    float Sum = 0.f;
#pragma unroll
    for (int p = 0; p < 16; ++p) Sum += red2[o16 * 16 + p];
    float inv = 1.f / Sum;

    float* wrow = w + ((size_t)(b * OO + obase + o16)) * CCH + part * 8;
#pragma unroll
    for (int j = 0; j < 8; ++j) wrow[j] = ev[j] * inv;
}

// ---------------- K1b: pack weights into fp16 MFMA B-fragments ----------------
// B of mfma_f32_16x16x32_f16: col = lane&15, per-lane 8 k-elems (same indexing as
// the A side in k2 — any internal k-permutation cancels between A and B).
// frag index: (((b*4 + kc)*4 + ot)*64 + lane), 16B per lane.
__global__ __launch_bounds__(256) void k1b_frag(const float* __restrict__ w,
                                                uint4* __restrict__ fragH) {
    const int b = blockIdx.x;
    const int kc = blockIdx.y;
    const int ot = threadIdx.x >> 6;
    const int lane = threadIdx.x & 63;
    const int o = ot * 16 + (lane & 15);
    const int cbase = kc * 32 + (lane >> 4) * 8;
    const float* wrow = w + ((size_t)(b * OO + o)) * CCH + cbase;

    float4 a = *(const float4*)wrow;
    float4 c = *(const float4*)(wrow + 4);
    v8h h;
    h[0] = (_Float16)a.x; h[1] = (_Float16)a.y;
    h[2] = (_Float16)a.z; h[3] = (_Float16)a.w;
    h[4] = (_Float16)c.x; h[5] = (_Float16)c.y;
    h[6] = (_Float16)c.z; h[7] = (_Float16)c.w;

    union { uint4 u; v8h v; } u;
    u.v = h;
    fragH[((b * 4 + kc) * 4 + ot) * 64 + lane] = u.u;
}

// ---------------- K2: out[b,t,o] = sum_c eeg[b,t,c] * w[b,o,c] via fp16 MFMA ----
// 256 thr = 4 waves; wave owns 64 t-rows (4 tiles of 16). A: lane holds
// eeg[row=lane&15][8 k-elems], converted fp32->fp16 (RNE) on the fly. fp16 rel
// err 2^-12 on both operands, fp32 accumulate => abs err ~3e-3 << 1.4e-2 thresh.
// C/D: col=lane&15, row=(lane>>4)*4+reg (HW-verified m89).
// RULE #20: every loop touching acc[][] is FULLY unrolled (partial unroll leaves
// a runtime index -> acc demoted to scratch; that was the R5 388MB-write bug).
// No min-waves clamp: let the allocator take ~110-130 VGPR.
__global__ __launch_bounds__(256) void k2_mfma(const float* __restrict__ eeg,
                                               const uint4* __restrict__ fragH,
                                               float* __restrict__ out) {
    const int b = blockIdx.y;
    const int t0 = blockIdx.x * 256;
    const int lane = threadIdx.x & 63;
    const int wv = __builtin_amdgcn_readfirstlane(threadIdx.x >> 6);
    const int r16 = lane & 15;
    const int kq = lane >> 4;

    const float* ebase = eeg + ((size_t)b * TT + t0 + wv * 64) * CCH;

    f32x4 acc[4][4];
#pragma unroll
    for (int tt = 0; tt < 4; ++tt)
#pragma unroll
        for (int ot = 0; ot < 4; ++ot)
            acc[tt][ot] = (f32x4){0.f, 0.f, 0.f, 0.f};

#pragma unroll 1
    for (int kc = 0; kc < 4; ++kc) {
        const uint4* fh = fragH + (size_t)((b * 4 + kc) * 4) * 64 + lane;
        v8h bh[4];
#pragma unroll
        for (int ot = 0; ot < 4; ++ot) {
            union { uint4 u; v8h v; } u;
            u.u = fh[ot * 64];
            bh[ot] = u.v;
        }
#pragma unroll
        for (int tt = 0; tt < 4; ++tt) {
            const float* ap = ebase + (size_t)(tt * 16 + r16) * CCH + kc * 32 + kq * 8;
            float4 v0 = *(const float4*)ap;
            float4 v1 = *(const float4*)(ap + 4);
            v8h ah;
            ah[0] = (_Float16)v0.x; ah[1] = (_Float16)v0.y;
            ah[2] = (_Float16)v0.z; ah[3] = (_Float16)v0.w;
            ah[4] = (_Float16)v1.x; ah[5] = (_Float16)v1.y;
            ah[6] = (_Float16)v1.z; ah[7] = (_Float16)v1.w;
#pragma unroll
            for (int ot = 0; ot < 4; ++ot) {
                acc[tt][ot] = __builtin_amdgcn_mfma_f32_16x16x32_f16(ah, bh[ot], acc[tt][ot], 0, 0, 0);
            }
        }
    }

    // epilogue: lane holds D[row = kq*4 + reg][col = r16] per tile
    const size_t orow0 = (size_t)b * TT + t0 + wv * 64;
#pragma unroll
    for (int tt = 0; tt < 4; ++tt) {
#pragma unroll
        for (int reg = 0; reg < 4; ++reg) {
            const size_t row = orow0 + tt * 16 + kq * 4 + reg;
#pragma unroll
            for (int ot = 0; ot < 4; ++ot) {
                out[row * OO + ot * 16 + r16] = acc[tt][ot][reg];
            }
        }
    }
}

extern "C" void kernel_launch(void* const* d_in, const int* in_sizes, int n_in,
                              void* d_out, int out_size, void* d_ws, size_t ws_size,
                              hipStream_t stream) {
    const float* eeg   = (const float*)d_in[0];   // [B,T,C]
    const float* pos   = (const float*)d_in[1];   // [B,C,2]
    const float* heads = (const float*)d_in[2];   // [O,D]
    float* out = (float*)d_out;                   // [B,T,O]

    char* ws = (char*)d_ws;
    float* Ht     = (float*)ws;                       // 288*64*4    = 73728 B
    float* w      = (float*)(ws + 73728);             // 32*64*128*4 = 1048576 B
    uint4* fragH  = (uint4*)(ws + 73728 + 1048576);   // 32*4*4*64*16 = 524288 B

    k0_transpose_heads<<<(OO * DD + 255) / 256, 256, 0, stream>>>(heads, Ht);
    k1_weights<<<dim3(BB, 4), 256, 0, stream>>>(pos, Ht, w);
    k1b_frag<<<dim3(BB, 4), 256, 0, stream>>>(w, fragH);
    k2_mfma<<<dim3(TT / 256, BB), 256, 0, stream>>>(eeg, fragH, out);
}